// Round 2
// baseline (1877.612 us; speedup 1.0000x reference)
//
#include <hip/hip_runtime.h>
#include <hip/hip_fp16.h>

#define NSENS 4
#define NB    64
#define LIN   2048
#define C1N   32
#define LP1   512
#define C2N   64
#define SEQ   256
#define DM    64
#define H1S   516

#define DOT64(res, xa, wp) { \
  float _a0=0.f,_a1=0.f,_a2=0.f,_a3=0.f; \
  _Pragma("unroll") \
  for (int _c = 0; _c < 64; _c += 4) { \
    _a0 = fmaf((xa)[_c],   (wp)[_c],   _a0); \
    _a1 = fmaf((xa)[_c+1], (wp)[_c+1], _a1); \
    _a2 = fmaf((xa)[_c+2], (wp)[_c+2], _a2); \
    _a3 = fmaf((xa)[_c+3], (wp)[_c+3], _a3); \
  } \
  (res) = (_a0+_a1)+(_a2+_a3); \
}

// 8 fp16 values <-> 8 floats through one 16B LDS transaction
__device__ __forceinline__ void rchunk8(const char* p, float* o) {
  const uint4 w = *(const uint4*)p;
  __half2 h0 = *(const __half2*)&w.x;
  __half2 h1 = *(const __half2*)&w.y;
  __half2 h2 = *(const __half2*)&w.z;
  __half2 h3 = *(const __half2*)&w.w;
  float2 f;
  f = __half22float2(h0); o[0]=f.x; o[1]=f.y;
  f = __half22float2(h1); o[2]=f.x; o[3]=f.y;
  f = __half22float2(h2); o[4]=f.x; o[5]=f.y;
  f = __half22float2(h3); o[6]=f.x; o[7]=f.y;
}
__device__ __forceinline__ void wchunk8(char* p, const float* v) {
  __half2 h0 = __floats2half2_rn(v[0],v[1]);
  __half2 h1 = __floats2half2_rn(v[2],v[3]);
  __half2 h2 = __floats2half2_rn(v[4],v[5]);
  __half2 h3 = __floats2half2_rn(v[6],v[7]);
  uint4 w;
  w.x = *(const unsigned*)&h0; w.y = *(const unsigned*)&h1;
  w.z = *(const unsigned*)&h2; w.w = *(const unsigned*)&h3;
  *(uint4*)p = w;
}

// ------------------------- conv branch kernel (unchanged) -------------------------
__global__ __launch_bounds__(256) void conv_kernel(
    const float* __restrict__ sens,
    const float* __restrict__ c1w, const float* __restrict__ c1b,
    const float* __restrict__ bn1g, const float* __restrict__ bn1b,
    const float* __restrict__ c2w, const float* __restrict__ c2b,
    const float* __restrict__ bn2g, const float* __restrict__ bn2b,
    float* __restrict__ x0)
{
  const int bid = blockIdx.x;
  const int s = bid >> 6, b = bid & 63;
  const int tid = threadIdx.x;
  __shared__ __half h1p[C1N][H1S];
  __shared__ float w2s[C1N*3*C2N];

  for (int i = tid; i < C1N*3*C2N; i += 256) {
    int co = i & 63; int rem = i >> 6; int k = rem % 3; int ci = rem / 3;
    w2s[(ci*3 + k)*64 + co] = c2w[((s*C2N + co)*C1N + ci)*3 + k];
  }

  const float* xg = sens + (size_t)(s*NB + b)*LIN;
  const float bnr = rsqrtf(1.0f + 1e-5f);

  {
    const int c = tid & 31;
    const int l0 = tid >> 5;
    const float w0 = c1w[(s*C1N + c)*5 + 0];
    const float w1 = c1w[(s*C1N + c)*5 + 1];
    const float w2 = c1w[(s*C1N + c)*5 + 2];
    const float w3 = c1w[(s*C1N + c)*5 + 3];
    const float w4 = c1w[(s*C1N + c)*5 + 4];
    const float cb = c1b[s*C1N + c];
    const float sc = bn1g[s*C1N + c]*bnr;
    const float bt = bn1b[s*C1N + c];
    for (int l = l0; l < LP1; l += 8) {
      const int base = 4*l;
      float xm2 = (base-2 >= 0) ? xg[base-2] : 0.f;
      float xm1 = (base-1 >= 0) ? xg[base-1] : 0.f;
      float x0v = xg[base+0];
      float x1v = xg[base+1];
      float x2v = xg[base+2];
      float x3v = xg[base+3];
      float x4v = (base+4 < LIN) ? xg[base+4] : 0.f;
      float y0 = w0*xm2 + w1*xm1 + w2*x0v + w3*x1v + w4*x2v;
      float y1 = w0*x0v + w1*x1v + w2*x2v + w3*x3v + w4*x4v;
      y0 = (y0 + cb)*sc + bt;
      y1 = (y1 + cb)*sc + bt;
      h1p[c][l+1] = __float2half(fmaxf(fmaxf(y0, y1), 0.f));
      if (l == 0)      h1p[c][0]      = __float2half(0.f);
      if (l == LP1-1)  h1p[c][LP1+1]  = __float2half(0.f);
    }
  }
  __syncthreads();

  const int rg = tid & 31, cg = tid >> 5;
  const int c0 = cg*8;
  float cb2[8], sc2[8], bt2[8];
  #pragma unroll
  for (int cc = 0; cc < 8; ++cc) {
    cb2[cc] = c2b[s*C2N + c0 + cc];
    sc2[cc] = bn2g[s*C2N + c0 + cc]*bnr;
    bt2[cc] = bn2b[s*C2N + c0 + cc];
  }
  for (int it = 0; it < 4; ++it) {
    const int rA = 64*it + rg;
    const int rB = rA + 32;
    float acc[2][2][8] = {};
    for (int ci = 0; ci < C1N; ++ci) {
      const __half2 a01 = *(const __half2*)&h1p[ci][2*rA];
      const __half2 a23 = *(const __half2*)&h1p[ci][2*rA+2];
      const __half2 b01 = *(const __half2*)&h1p[ci][2*rB];
      const __half2 b23 = *(const __half2*)&h1p[ci][2*rB+2];
      const float hA[4] = { __low2float(a01), __high2float(a01), __low2float(a23), __high2float(a23) };
      const float hB[4] = { __low2float(b01), __high2float(b01), __low2float(b23), __high2float(b23) };
      #pragma unroll
      for (int k = 0; k < 3; ++k) {
        const float4 wv0 = *(const float4*)&w2s[(ci*3+k)*64 + c0];
        const float4 wv1 = *(const float4*)&w2s[(ci*3+k)*64 + c0 + 4];
        const float wr[8] = {wv0.x, wv0.y, wv0.z, wv0.w, wv1.x, wv1.y, wv1.z, wv1.w};
        #pragma unroll
        for (int p = 0; p < 2; ++p) {
          const float xa = hA[k+p];
          const float xb = hB[k+p];
          #pragma unroll
          for (int cc = 0; cc < 8; ++cc) {
            acc[0][p][cc] = fmaf(wr[cc], xa, acc[0][p][cc]);
            acc[1][p][cc] = fmaf(wr[cc], xb, acc[1][p][cc]);
          }
        }
      }
    }
    #pragma unroll
    for (int rr = 0; rr < 2; ++rr) {
      const int r = rr ? rB : rA;
      float* outp = x0 + ((size_t)bid*SEQ + r)*DM + c0;
      #pragma unroll
      for (int cc = 0; cc < 8; ++cc) {
        float v0 = (acc[rr][0][cc] + cb2[cc])*sc2[cc] + bt2[cc];
        float v1 = (acc[rr][1][cc] + cb2[cc])*sc2[cc] + bt2[cc];
        float v = fmaxf(fmaxf(v0, v1), 0.f);
        const int d = c0 + cc;
        const float ang = (float)r * __expf(-0.14391156463f*(float)(d & ~1));
        const float pe = (d & 1) ? cosf(ang) : sinf(ang);
        outp[cc] = v + pe;
      }
    }
  }
}

// ------------------------- transformer kernel v2: 1024 threads -------------------------
// LDS map (136 KiB):
//   [0      , 32K )  xs  : __half [256 rows][64], row=128B, XOR-swizzle ((r&7)<<4)
//   [32K    , 40K )  lnb : float  [4][256][2]  (LN partials; reused for final mean)
//   [40K    , 72K )  Ks  : __half [j:256][h:8][8], row=128B, XOR ((j&7)<<4)
//   [72K    , 136K)  Vs  : float  [j:256][h:8][8], row=256B, XOR ((j&7)<<4) per 16B
//   ffh (FF hidden, fp16 [256][128], row=256B, XOR ((r&7)<<4)) overlays [40K,104K)
__global__ __launch_bounds__(1024) void tx_kernel(
  const float* __restrict__ x0, float* __restrict__ nf,
  const float* __restrict__ wqkv, const float* __restrict__ bqkv,
  const float* __restrict__ wo, const float* __restrict__ bo,
  const float* __restrict__ ln1g, const float* __restrict__ ln1b,
  const float* __restrict__ fw1, const float* __restrict__ fb1,
  const float* __restrict__ fw2, const float* __restrict__ fb2,
  const float* __restrict__ ln2g, const float* __restrict__ ln2b)
{
  __shared__ char smem[139264];
  __half* xs  = (__half*)(smem);
  float*  lnb = (float*)(smem + 32768);
  __half* Ks  = (__half*)(smem + 40960);
  float*  Vs  = (float*)(smem + 73728);
  char*   ffb = smem + 40960;

  const int bid = blockIdx.x;
  const int s = bid >> 6, b = bid & 63;
  const int t = threadIdx.x;
  const int r = t & 255;                                  // sequence row
  const int sub = __builtin_amdgcn_readfirstlane(t >> 8); // wave-group: dim quarter (SGPR!)
  const int db = sub*16;                                  // my 16 output dims
  const int rs = (r & 7) << 4;                            // row swizzle
  char* xrb = (char*)xs + r*128;

  // ---- load x0 row r, dims db..db+15 ----
  {
    const float* xp = x0 + ((size_t)bid*SEQ + r)*DM + db;
    float v[16];
    #pragma unroll
    for (int i = 0; i < 16; i += 4) {
      float4 q4 = *(const float4*)(xp + i);
      v[i]=q4.x; v[i+1]=q4.y; v[i+2]=q4.z; v[i+3]=q4.w;
    }
    wchunk8(xrb + (((2*sub  )*16) ^ rs), v);
    wchunk8(xrb + (((2*sub+1)*16) ^ rs), v+8);
  }
  __syncthreads();

  const float qs = 0.35355339059327373f * 1.4426950408889634f; // 1/sqrt(8)*log2(e)

  for (int layer = 0; layer < 2; ++layer) {
    const int wi = s*2 + layer;
    const float* Wq  = wqkv + (size_t)wi*192*64;
    const float* Bq  = bqkv + wi*192;
    const float* Wo  = wo   + (size_t)wi*64*64;
    const float* Bo  = bo   + wi*64;
    const float* G1  = ln1g + wi*64;  const float* B1 = ln1b + wi*64;
    const float* W1  = fw1  + (size_t)wi*256*64;  const float* Bf1 = fb1 + wi*256;
    const float* W2  = fw2  + (size_t)wi*64*256;  const float* Bf2 = fb2 + wi*64;
    const float* G2  = ln2g + wi*64;  const float* B2 = ln2b + wi*64;

    // ---- QKV: this thread computes q/k/v dims db..db+15 of row r ----
    float q[16];
    {
      float row[64];
      #pragma unroll
      for (int cc = 0; cc < 8; ++cc) rchunk8(xrb + ((cc*16) ^ rs), row + cc*8);
      #pragma unroll
      for (int i = 0; i < 16; ++i) {
        float d_; DOT64(d_, row, Wq + (db+i)*64);
        q[i] = (d_ + Bq[db+i]) * qs;
      }
      char* kb = (char*)Ks + r*128;
      #pragma unroll
      for (int hf = 0; hf < 2; ++hf) {
        float kk[8];
        #pragma unroll
        for (int i = 0; i < 8; ++i) {
          float d_; DOT64(d_, row, Wq + (64+db+hf*8+i)*64);
          kk[i] = d_ + Bq[64+db+hf*8+i];
        }
        wchunk8(kb + (((2*sub+hf)*16) ^ rs), kk);
      }
      char* vb = (char*)Vs + r*256;
      #pragma unroll
      for (int hf = 0; hf < 2; ++hf) {
        float vv[8];
        #pragma unroll
        for (int i = 0; i < 8; ++i) {
          float d_; DOT64(d_, row, Wq + (128+db+hf*8+i)*64);
          vv[i] = d_ + Bq[128+db+hf*8+i];
        }
        const int so = (2*sub+hf)*32;
        *(float4*)(vb + ((so     ) ^ rs)) = make_float4(vv[0],vv[1],vv[2],vv[3]);
        *(float4*)(vb + ((so + 16) ^ rs)) = make_float4(vv[4],vv[5],vv[6],vv[7]);
      }
    }
    __syncthreads();

    // ---- attention: 2 heads per thread; K/V reads are wave-uniform (broadcast) ----
    float attv[16];
    #pragma unroll
    for (int hf = 0; hf < 2; ++hf) {
      const int h = 2*sub + hf;
      float a0=0.f,a1=0.f,a2=0.f,a3=0.f,a4=0.f,a5=0.f,a6=0.f,a7=0.f,lsum=0.f;
      const float q0=q[hf*8+0],q1=q[hf*8+1],q2=q[hf*8+2],q3=q[hf*8+3];
      const float q4=q[hf*8+4],q5=q[hf*8+5],q6=q[hf*8+6],q7=q[hf*8+7];
      #pragma unroll 4
      for (int j = 0; j < SEQ; ++j) {
        const int jsw = (j&7)<<4;
        const uint4 kw = *(const uint4*)((const char*)Ks + j*128 + ((h*16) ^ jsw));
        __half2 h0 = *(const __half2*)&kw.x;
        __half2 h1 = *(const __half2*)&kw.y;
        __half2 h2 = *(const __half2*)&kw.z;
        __half2 h3 = *(const __half2*)&kw.w;
        float2 f0 = __half22float2(h0), f1 = __half22float2(h1);
        float2 f2 = __half22float2(h2), f3 = __half22float2(h3);
        float sA = fmaf(q0,f0.x, q1*f0.y) + fmaf(q2,f1.x, q3*f1.y);
        float sB = fmaf(q4,f2.x, q5*f2.y) + fmaf(q6,f3.x, q7*f3.y);
        float p = exp2f(sA + sB);           // scores bounded -> max-free softmax
        const char* vb = (const char*)Vs + j*256;
        float4 v0 = *(const float4*)(vb + ((h*32     ) ^ jsw));
        float4 v1 = *(const float4*)(vb + ((h*32 + 16) ^ jsw));
        lsum += p;
        a0 = fmaf(p, v0.x, a0); a1 = fmaf(p, v0.y, a1);
        a2 = fmaf(p, v0.z, a2); a3 = fmaf(p, v0.w, a3);
        a4 = fmaf(p, v1.x, a4); a5 = fmaf(p, v1.y, a5);
        a6 = fmaf(p, v1.z, a6); a7 = fmaf(p, v1.w, a7);
      }
      const float inv = 1.0f / lsum;
      attv[hf*8+0]=a0*inv; attv[hf*8+1]=a1*inv; attv[hf*8+2]=a2*inv; attv[hf*8+3]=a3*inv;
      attv[hf*8+4]=a4*inv; attv[hf*8+5]=a5*inv; attv[hf*8+6]=a6*inv; attv[hf*8+7]=a7*inv;
    }
    // residual (own chunks) then overwrite xs with attention output (own chunks only)
    float res[16];
    rchunk8(xrb + (((2*sub  )*16) ^ rs), res);
    rchunk8(xrb + (((2*sub+1)*16) ^ rs), res+8);
    wchunk8(xrb + (((2*sub  )*16) ^ rs), attv);
    wchunk8(xrb + (((2*sub+1)*16) ^ rs), attv+8);
    __syncthreads();

    // ---- O-projection + residual + LN1 ----
    float y[16];
    {
      float arow[64];
      #pragma unroll
      for (int cc = 0; cc < 8; ++cc) rchunk8(xrb + ((cc*16) ^ rs), arow + cc*8);
      float p1 = 0.f, p2 = 0.f;
      #pragma unroll
      for (int i = 0; i < 16; ++i) {
        float d_; DOT64(d_, arow, Wo + (db+i)*64);
        y[i] = d_ + Bo[db+i] + res[i];
        p1 += y[i]; p2 = fmaf(y[i], y[i], p2);
      }
      lnb[(sub*SEQ + r)*2    ] = p1;
      lnb[(sub*SEQ + r)*2 + 1] = p2;
    }
    __syncthreads();
    {
      float t1 = lnb[(0*SEQ+r)*2] + lnb[(1*SEQ+r)*2] + lnb[(2*SEQ+r)*2] + lnb[(3*SEQ+r)*2];
      float t2 = lnb[(0*SEQ+r)*2+1] + lnb[(1*SEQ+r)*2+1] + lnb[(2*SEQ+r)*2+1] + lnb[(3*SEQ+r)*2+1];
      const float mean = t1 * (1.0f/64.0f);
      const float var  = t2 * (1.0f/64.0f) - mean*mean;
      const float rstd = rsqrtf(var + 1e-5f);
      float xn[16];
      #pragma unroll
      for (int i = 0; i < 16; ++i)
        xn[i] = (y[i]-mean)*rstd*G1[db+i] + B1[db+i];
      wchunk8(xrb + (((2*sub  )*16) ^ rs), xn);
      wchunk8(xrb + (((2*sub+1)*16) ^ rs), xn+8);
    }
    __syncthreads();

    // ---- FF: 64->256 gelu ->64 in two 128-hidden passes (ffh overlays K/V) ----
    float out16[16] = {0.f,0.f,0.f,0.f,0.f,0.f,0.f,0.f,0.f,0.f,0.f,0.f,0.f,0.f,0.f,0.f};
    float row2[64];
    #pragma unroll
    for (int cc = 0; cc < 8; ++cc) rchunk8(xrb + ((cc*16) ^ rs), row2 + cc*8);
    char* frb = ffb + r*256;
    for (int pass = 0; pass < 2; ++pass) {
      #pragma unroll
      for (int g = 0; g < 2; ++g) {
        float hv[16];
        #pragma unroll
        for (int i = 0; i < 16; ++i) {
          const int hi = pass*128 + sub*32 + g*16 + i;
          float d_; DOT64(d_, row2, W1 + hi*64);
          d_ += Bf1[hi];
          hv[i] = 0.5f*d_*(1.0f + erff(d_*0.70710678118654752f));
        }
        wchunk8(frb + (((sub*4+g*2  )*16) ^ rs), hv);
        wchunk8(frb + (((sub*4+g*2+1)*16) ^ rs), hv+8);
      }
      __syncthreads();
      #pragma unroll
      for (int cc = 0; cc < 16; ++cc) {
        float gv[8]; rchunk8(frb + ((cc*16) ^ rs), gv);
        #pragma unroll
        for (int i = 0; i < 16; ++i) {
          const float* w = W2 + (db+i)*256 + pass*128 + cc*8;
          float acc = out16[i];
          acc = fmaf(gv[0], w[0], acc); acc = fmaf(gv[1], w[1], acc);
          acc = fmaf(gv[2], w[2], acc); acc = fmaf(gv[3], w[3], acc);
          acc = fmaf(gv[4], w[4], acc); acc = fmaf(gv[5], w[5], acc);
          acc = fmaf(gv[6], w[6], acc); acc = fmaf(gv[7], w[7], acc);
          out16[i] = acc;
        }
      }
      __syncthreads();
    }
    // residual + LN2
    {
      float res2[16];
      rchunk8(xrb + (((2*sub  )*16) ^ rs), res2);
      rchunk8(xrb + (((2*sub+1)*16) ^ rs), res2+8);
      float yv[16]; float t1 = 0.f, t2 = 0.f;
      #pragma unroll
      for (int i = 0; i < 16; ++i) {
        yv[i] = out16[i] + Bf2[db+i] + res2[i];
        t1 += yv[i]; t2 = fmaf(yv[i], yv[i], t2);
      }
      lnb[(sub*SEQ + r)*2    ] = t1;
      lnb[(sub*SEQ + r)*2 + 1] = t2;
      __syncthreads();
      float s1 = lnb[(0*SEQ+r)*2] + lnb[(1*SEQ+r)*2] + lnb[(2*SEQ+r)*2] + lnb[(3*SEQ+r)*2];
      float s2 = lnb[(0*SEQ+r)*2+1] + lnb[(1*SEQ+r)*2+1] + lnb[(2*SEQ+r)*2+1] + lnb[(3*SEQ+r)*2+1];
      const float mean = s1 * (1.0f/64.0f);
      const float var  = s2 * (1.0f/64.0f) - mean*mean;
      const float rstd = rsqrtf(var + 1e-5f);
      float xn[16];
      #pragma unroll
      for (int i = 0; i < 16; ++i)
        xn[i] = (yv[i]-mean)*rstd*G2[db+i] + B2[db+i];
      wchunk8(xrb + (((2*sub  )*16) ^ rs), xn);
      wchunk8(xrb + (((2*sub+1)*16) ^ rs), xn+8);
    }
    __syncthreads();
  }

  // ---- mean over sequence -> nf[b][s][d] ----
  if (t < 256) {
    const int d = t & 63, qu = t >> 6;
    const int coff = ((d>>3)<<4);
    const int lo = (d&7)<<1;
    float sm = 0.f;
    for (int rr = qu*64; rr < qu*64 + 64; ++rr) {
      const char* p = (const char*)xs + rr*128 + ((coff ^ ((rr&7)<<4)) + lo);
      sm += __half2float(*(const __half*)p);
    }
    lnb[qu*64 + d] = sm;
  }
  __syncthreads();
  if (t < 64) {
    float sm = lnb[t] + lnb[64+t] + lnb[128+t] + lnb[192+t];
    nf[((size_t)b*4 + s)*64 + t] = sm * (1.0f/256.0f);
  }
}

// ------------------------- graph head kernel (unchanged) -------------------------
__global__ __launch_bounds__(128) void head_kernel(
  const float* __restrict__ nf,
  const float* __restrict__ ws_w, const float* __restrict__ ws_b,
  const float* __restrict__ b_s,  const float* __restrict__ lambda_init,
  const float* __restrict__ mc_w1, const float* __restrict__ mc_b1,
  const float* __restrict__ mc_w2, const float* __restrict__ mc_b2,
  const float* __restrict__ g1w, const float* __restrict__ g1b,
  const float* __restrict__ g2w, const float* __restrict__ g2b,
  const float* __restrict__ cw1, const float* __restrict__ cb1,
  const float* __restrict__ cw2, const float* __restrict__ cb2,
  float* __restrict__ out)
{
  const int b = blockIdx.x, t = threadIdx.x;
  __shared__ float nfb[256];
  __shared__ float meannf[64];
  __shared__ float fafb[8];
  __shared__ float z1[32];
  __shared__ float normM[16];
  __shared__ float rs[4];
  __shared__ float xw[512];
  __shared__ float hmat[512];
  __shared__ float hw[1024];
  __shared__ float gv[256];
  __shared__ float r1[128];

  for (int i = t; i < 256; i += 128) nfb[i] = nf[b*256 + i];
  __syncthreads();
  if (t < 8) {
    const int i = t & 3;
    const float* w = ws_w + (t >> 2)*64;
    float acc = 0.f;
    for (int c = 0; c < 64; ++c) acc = fmaf(nfb[i*64+c], w[c], acc);
    fafb[t] = acc;
  }
  if (t >= 64 && t < 128) {
    const int d = t - 64;
    meannf[d] = 0.25f*(nfb[d] + nfb[64+d] + nfb[128+d] + nfb[192+d]);
  }
  __syncthreads();
  if (t < 32) {
    float acc = mc_b1[t];
    const float* w = mc_w1 + t*64;
    for (int c = 0; c < 64; ++c) acc = fmaf(meannf[c], w[c], acc);
    z1[t] = fmaxf(acc, 0.f);
  }
  __syncthreads();
  if (t == 0) {
    float li = mc_b2[0];
    for (int k = 0; k < 32; ++k) li = fmaf(z1[k], mc_w2[k], li);
    const float lam = (1.0f/(1.0f + __expf(-li))) * lambda_init[0];
    const float AB[4][4] = {{1,1,0,0},{1,1,1,1},{0,1,1,1},{0,1,1,1}};
    const float add = ws_b[0] + b_s[0];
    float sM[4][4], deg[4];
    for (int i = 0; i < 4; ++i) {
      float d_ = 0.f;
      for (int j = 0; j < 4; ++j) {
        sM[i][j] = 1.0f/(1.0f + __expf(-(fafb[i] + fafb[4+j] + add)));
        d_ += sM[i][j];
      }
      deg[i] = d_;
    }
    float A[4][4], dinv[4];
    for (int i = 0; i < 4; ++i)
      for (int j = 0; j < 4; ++j) {
        const float a_ = sM[i][j] / (deg[j] + 1e-8f);
        const float sh = fmaxf(a_ * AB[i][j], 0.f);
        A[i][j] = lam*((i==j) ? 1.f : 0.f) + (1.0f - lam)*sh;
      }
    for (int j = 0; j < 4; ++j) {
      float d_ = 0.f;
      for (int i = 0; i < 4; ++i) d_ += A[i][j];
      dinv[j] = (d_ > 0.f) ? rsqrtf(d_) : 0.f;
    }
    for (int i = 0; i < 4; ++i) {
      float r_ = 0.f;
      for (int j = 0; j < 4; ++j) {
        const float n_ = dinv[i]*A[i][j]*dinv[j];
        normM[i*4+j] = n_;
        r_ += n_;
      }
      rs[i] = r_;
    }
  }
  __syncthreads();
  for (int idx = t; idx < 512; idx += 128) {
    const int i = idx >> 7, f = idx & 127;
    float acc = 0.f;
    for (int c = 0; c < 64; ++c) acc = fmaf(nfb[i*64+c], g1w[c*128 + f], acc);
    xw[idx] = acc;
  }
  __syncthreads();
  for (int idx = t; idx < 512; idx += 128) {
    const int j = idx >> 7, f = idx & 127;
    float acc = g1b[f];
    #pragma unroll
    for (int i = 0; i < 4; ++i) acc = fmaf(normM[i*4+j], xw[i*128+f], acc);
    hmat[j*128+f] = fmaxf(acc, 0.f);
  }
  __syncthreads();
  for (int idx = t; idx < 1024; idx += 128) {
    const int i = idx >> 8, f = idx & 255;
    float acc = 0.f;
    for (int c = 0; c < 128; ++c) acc = fmaf(hmat[i*128+c], g2w[c*256+f], acc);
    hw[idx] = acc;
  }
  __syncthreads();
  for (int f = t; f < 256; f += 128) {
    float acc = 0.f;
    #pragma unroll
    for (int i = 0; i < 4; ++i) acc = fmaf(rs[i], hw[i*256+f], acc);
    gv[f] = 0.25f*acc + g2b[f];
  }
  __syncthreads();
  if (t < 128) {
    float acc = cb1[t];
    for (int c = 0; c < 256; ++c) acc = fmaf(gv[c], cw1[c*128+t], acc);
    r1[t] = fmaxf(acc, 0.f);
  }
  __syncthreads();
  if (t < 5) {
    float acc = cb2[t];
    for (int k = 0; k < 128; ++k) acc = fmaf(r1[k], cw2[k*5 + t], acc);
    out[b*5 + t] = acc;
  }
}

// ------------------------- launch -------------------------
extern "C" void kernel_launch(void* const* d_in, const int* in_sizes, int n_in,
                              void* d_out, int out_size, void* d_ws, size_t ws_size,
                              hipStream_t stream) {
  (void)in_sizes; (void)n_in; (void)out_size; (void)ws_size;
  const float* sens   = (const float*)d_in[0];
  const float* c1w    = (const float*)d_in[1];
  const float* c1b    = (const float*)d_in[2];
  const float* bn1g   = (const float*)d_in[3];
  const float* bn1b   = (const float*)d_in[4];
  const float* c2w    = (const float*)d_in[5];
  const float* c2b    = (const float*)d_in[6];
  const float* bn2g   = (const float*)d_in[7];
  const float* bn2b   = (const float*)d_in[8];
  const float* wqkv   = (const float*)d_in[9];
  const float* bqkv   = (const float*)d_in[10];
  const float* wo     = (const float*)d_in[11];
  const float* bo     = (const float*)d_in[12];
  const float* ln1g   = (const float*)d_in[13];
  const float* ln1b   = (const float*)d_in[14];
  const float* fw1    = (const float*)d_in[15];
  const float* fb1    = (const float*)d_in[16];
  const float* fw2    = (const float*)d_in[17];
  const float* fb2    = (const float*)d_in[18];
  const float* ln2g   = (const float*)d_in[19];
  const float* ln2b   = (const float*)d_in[20];
  const float* ws_w   = (const float*)d_in[21];
  const float* ws_b   = (const float*)d_in[22];
  const float* b_s    = (const float*)d_in[23];
  const float* lam0   = (const float*)d_in[24];
  const float* mc_w1  = (const float*)d_in[25];
  const float* mc_b1  = (const float*)d_in[26];
  const float* mc_w2  = (const float*)d_in[27];
  const float* mc_b2  = (const float*)d_in[28];
  const float* g1w    = (const float*)d_in[29];
  const float* g1b    = (const float*)d_in[30];
  const float* g2w    = (const float*)d_in[31];
  const float* g2b    = (const float*)d_in[32];
  const float* cw1    = (const float*)d_in[33];
  const float* cb1    = (const float*)d_in[34];
  const float* cw2    = (const float*)d_in[35];
  const float* cb2    = (const float*)d_in[36];

  float* x0 = (float*)d_ws;
  float* nf = (float*)((char*)d_ws + (size_t)NSENS*NB*SEQ*DM*4);

  conv_kernel<<<NSENS*NB, 256, 0, stream>>>(sens, c1w, c1b, bn1g, bn1b,
                                            c2w, c2b, bn2g, bn2b, x0);
  tx_kernel<<<NSENS*NB, 1024, 0, stream>>>(x0, nf, wqkv, bqkv, wo, bo,
                                           ln1g, ln1b, fw1, fb1, fw2, fb2, ln2g, ln2b);
  head_kernel<<<NB, 128, 0, stream>>>(nf, ws_w, ws_b, b_s, lam0,
                                      mc_w1, mc_b1, mc_w2, mc_b2,
                                      g1w, g1b, g2w, g2b, cw1, cb1, cw2, cb2,
                                      (float*)d_out);
}

// Round 4
// 1103.423 us; speedup vs baseline: 1.7016x; 1.7016x over previous
//
#include <hip/hip_runtime.h>
#include <hip/hip_fp16.h>

#define NSENS 4
#define NB    64
#define LIN   2048
#define C1N   32
#define LP1   512
#define C2N   64
#define SEQ   256
#define DM    64
#define H1S   516

#define DOT64(res, xa, wp) { \
  float _a0=0.f,_a1=0.f,_a2=0.f,_a3=0.f; \
  _Pragma("unroll") \
  for (int _c = 0; _c < 64; _c += 4) { \
    _a0 = fmaf((xa)[_c],   (wp)[_c],   _a0); \
    _a1 = fmaf((xa)[_c+1], (wp)[_c+1], _a1); \
    _a2 = fmaf((xa)[_c+2], (wp)[_c+2], _a2); \
    _a3 = fmaf((xa)[_c+3], (wp)[_c+3], _a3); \
  } \
  (res) = (_a0+_a1)+(_a2+_a3); \
}

// 8 fp16 values <-> 8 floats through one 16B LDS transaction
__device__ __forceinline__ void rchunk8(const char* p, float* o) {
  const uint4 w = *(const uint4*)p;
  __half2 h0 = *(const __half2*)&w.x;
  __half2 h1 = *(const __half2*)&w.y;
  __half2 h2 = *(const __half2*)&w.z;
  __half2 h3 = *(const __half2*)&w.w;
  float2 f;
  f = __half22float2(h0); o[0]=f.x; o[1]=f.y;
  f = __half22float2(h1); o[2]=f.x; o[3]=f.y;
  f = __half22float2(h2); o[4]=f.x; o[5]=f.y;
  f = __half22float2(h3); o[6]=f.x; o[7]=f.y;
}
__device__ __forceinline__ void wchunk8(char* p, const float* v) {
  __half2 h0 = __floats2half2_rn(v[0],v[1]);
  __half2 h1 = __floats2half2_rn(v[2],v[3]);
  __half2 h2 = __floats2half2_rn(v[4],v[5]);
  __half2 h3 = __floats2half2_rn(v[6],v[7]);
  uint4 w;
  w.x = *(const unsigned*)&h0; w.y = *(const unsigned*)&h1;
  w.z = *(const unsigned*)&h2; w.w = *(const unsigned*)&h3;
  *(uint4*)p = w;
}

// ------------------------- conv branch kernel -------------------------
__global__ __launch_bounds__(256) void conv_kernel(
    const float* __restrict__ sens,
    const float* __restrict__ c1w, const float* __restrict__ c1b,
    const float* __restrict__ bn1g, const float* __restrict__ bn1b,
    const float* __restrict__ c2w, const float* __restrict__ c2b,
    const float* __restrict__ bn2g, const float* __restrict__ bn2b,
    float* __restrict__ x0)
{
  const int bid = blockIdx.x;
  const int s = bid >> 6, b = bid & 63;
  const int tid = threadIdx.x;
  __shared__ __half h1p[C1N][H1S];
  __shared__ float w2s[C1N*3*C2N];

  for (int i = tid; i < C1N*3*C2N; i += 256) {
    int co = i & 63; int rem = i >> 6; int k = rem % 3; int ci = rem / 3;
    w2s[(ci*3 + k)*64 + co] = c2w[((s*C2N + co)*C1N + ci)*3 + k];
  }

  const float* xg = sens + (size_t)(s*NB + b)*LIN;
  const float bnr = rsqrtf(1.0f + 1e-5f);

  {
    const int c = tid & 31;
    const int l0 = tid >> 5;
    const float w0 = c1w[(s*C1N + c)*5 + 0];
    const float w1 = c1w[(s*C1N + c)*5 + 1];
    const float w2 = c1w[(s*C1N + c)*5 + 2];
    const float w3 = c1w[(s*C1N + c)*5 + 3];
    const float w4 = c1w[(s*C1N + c)*5 + 4];
    const float cb = c1b[s*C1N + c];
    const float sc = bn1g[s*C1N + c]*bnr;
    const float bt = bn1b[s*C1N + c];
    for (int l = l0; l < LP1; l += 8) {
      const int base = 4*l;
      float xm2 = (base-2 >= 0) ? xg[base-2] : 0.f;
      float xm1 = (base-1 >= 0) ? xg[base-1] : 0.f;
      float x0v = xg[base+0];
      float x1v = xg[base+1];
      float x2v = xg[base+2];
      float x3v = xg[base+3];
      float x4v = (base+4 < LIN) ? xg[base+4] : 0.f;
      float y0 = w0*xm2 + w1*xm1 + w2*x0v + w3*x1v + w4*x2v;
      float y1 = w0*x0v + w1*x1v + w2*x2v + w3*x3v + w4*x4v;
      y0 = (y0 + cb)*sc + bt;
      y1 = (y1 + cb)*sc + bt;
      h1p[c][l+1] = __float2half(fmaxf(fmaxf(y0, y1), 0.f));
      if (l == 0)      h1p[c][0]      = __float2half(0.f);
      if (l == LP1-1)  h1p[c][LP1+1]  = __float2half(0.f);
    }
  }
  __syncthreads();

  const int rg = tid & 31, cg = tid >> 5;
  const int c0 = cg*8;
  float cb2[8], sc2[8], bt2[8];
  #pragma unroll
  for (int cc = 0; cc < 8; ++cc) {
    cb2[cc] = c2b[s*C2N + c0 + cc];
    sc2[cc] = bn2g[s*C2N + c0 + cc]*bnr;
    bt2[cc] = bn2b[s*C2N + c0 + cc];
  }
  for (int it = 0; it < 4; ++it) {
    const int rA = 64*it + rg;
    const int rB = rA + 32;
    float acc[2][2][8] = {};
    for (int ci = 0; ci < C1N; ++ci) {
      const __half2 a01 = *(const __half2*)&h1p[ci][2*rA];
      const __half2 a23 = *(const __half2*)&h1p[ci][2*rA+2];
      const __half2 b01 = *(const __half2*)&h1p[ci][2*rB];
      const __half2 b23 = *(const __half2*)&h1p[ci][2*rB+2];
      const float hA[4] = { __low2float(a01), __high2float(a01), __low2float(a23), __high2float(a23) };
      const float hB[4] = { __low2float(b01), __high2float(b01), __low2float(b23), __high2float(b23) };
      #pragma unroll
      for (int k = 0; k < 3; ++k) {
        const float4 wv0 = *(const float4*)&w2s[(ci*3+k)*64 + c0];
        const float4 wv1 = *(const float4*)&w2s[(ci*3+k)*64 + c0 + 4];
        const float wr[8] = {wv0.x, wv0.y, wv0.z, wv0.w, wv1.x, wv1.y, wv1.z, wv1.w};
        #pragma unroll
        for (int p = 0; p < 2; ++p) {
          const float xa = hA[k+p];
          const float xb = hB[k+p];
          #pragma unroll
          for (int cc = 0; cc < 8; ++cc) {
            acc[0][p][cc] = fmaf(wr[cc], xa, acc[0][p][cc]);
            acc[1][p][cc] = fmaf(wr[cc], xb, acc[1][p][cc]);
          }
        }
      }
    }
    #pragma unroll
    for (int rr = 0; rr < 2; ++rr) {
      const int r = rr ? rB : rA;
      float* outp = x0 + ((size_t)bid*SEQ + r)*DM + c0;
      #pragma unroll
      for (int cc = 0; cc < 8; ++cc) {
        float v0 = (acc[rr][0][cc] + cb2[cc])*sc2[cc] + bt2[cc];
        float v1 = (acc[rr][1][cc] + cb2[cc])*sc2[cc] + bt2[cc];
        float v = fmaxf(fmaxf(v0, v1), 0.f);
        const int d = c0 + cc;
        const float ang = (float)r * __expf(-0.14391156463f*(float)(d & ~1));
        const float pe = (d & 1) ? cosf(ang) : sinf(ang);
        outp[cc] = v + pe;
      }
    }
  }
}

// ---------- transformer kernel v4: 1024 threads, fp32 weights, 128-VGPR budget ----------
// LDS map (136 KiB):
//   [0   , 32K )  xs  : __half [256 rows][64] packed pairs, row=128B, XOR ((r&7)<<4)
//   [32K , 40K )  lnb : float  [4][256][2]
//   [40K , 72K )  Ks  : __half [j][h*8] packed, row=128B, XOR ((j&7)<<4)
//   [72K , 136K)  Vs  : float  [j][h*8], row=256B, XOR ((j&7)<<4) per 16B
//   ffb (fp16 [256][128] packed, row=256B, XOR) overlays [40K,104K)
__global__ __launch_bounds__(1024, 4) void tx_kernel(
  const float* __restrict__ x0, float* __restrict__ nf,
  const float* __restrict__ wqkv, const float* __restrict__ bqkv,
  const float* __restrict__ wo, const float* __restrict__ bo,
  const float* __restrict__ ln1g, const float* __restrict__ ln1b,
  const float* __restrict__ fw1, const float* __restrict__ fb1,
  const float* __restrict__ fw2, const float* __restrict__ fb2,
  const float* __restrict__ ln2g, const float* __restrict__ ln2b)
{
  __shared__ char smem[139264];
  __half* xs  = (__half*)(smem);
  float*  lnb = (float*)(smem + 32768);
  char*   Ksb = smem + 40960;
  char*   Vsb = smem + 73728;
  char*   ffb = smem + 40960;

  const int bid = blockIdx.x;
  const int s = bid >> 6, b = bid & 63;
  const int t = threadIdx.x;
  const int r = t & 255;
  const int sub = __builtin_amdgcn_readfirstlane(t >> 8);
  const int db = sub*16;
  const int rs = (r & 7) << 4;
  char* xrb = (char*)xs + r*128;

  // ---- load x0 row r, dims db..db+15, pack to fp16 ----
  {
    const float* xp = x0 + ((size_t)bid*SEQ + r)*DM + db;
    float v[16];
    #pragma unroll
    for (int i = 0; i < 16; i += 4) {
      float4 q4 = *(const float4*)(xp + i);
      v[i]=q4.x; v[i+1]=q4.y; v[i+2]=q4.z; v[i+3]=q4.w;
    }
    wchunk8(xrb + (((2*sub  )*16) ^ rs), v);
    wchunk8(xrb + (((2*sub+1)*16) ^ rs), v+8);
  }
  __syncthreads();

  const float qs = 0.35355339059327373f * 1.4426950408889634f; // 1/sqrt(8)*log2(e)

  for (int layer = 0; layer < 2; ++layer) {
    const int wi = s*2 + layer;
    const float* Wq  = wqkv + (size_t)wi*192*64;
    const float* Bq  = bqkv + wi*192;
    const float* Wo  = wo   + (size_t)wi*64*64;
    const float* Bo  = bo   + wi*64;
    const float* G1  = ln1g + wi*64;  const float* B1 = ln1b + wi*64;
    const float* W1  = fw1  + (size_t)wi*256*64;  const float* Bf1 = fb1 + wi*256;
    const float* W2  = fw2  + (size_t)wi*64*256;  const float* Bf2 = fb2 + wi*64;
    const float* G2  = ln2g + wi*64;  const float* B2 = ln2b + wi*64;

    // ---- QKV: this thread computes q/k/v dims db..db+15 of row r ----
    float q[16];
    {
      float row[64];
      #pragma unroll
      for (int cc = 0; cc < 8; ++cc) rchunk8(xrb + ((cc*16) ^ rs), row + cc*8);
      #pragma unroll
      for (int i = 0; i < 16; ++i) {
        float d_; DOT64(d_, row, Wq + (db+i)*64);
        q[i] = (d_ + Bq[db+i]) * qs;
      }
      char* kb = Ksb + r*128;
      #pragma unroll
      for (int hf = 0; hf < 2; ++hf) {
        float kk[8];
        #pragma unroll
        for (int i = 0; i < 8; ++i) {
          float d_; DOT64(d_, row, Wq + (64+db+hf*8+i)*64);
          kk[i] = d_ + Bq[64+db+hf*8+i];
        }
        wchunk8(kb + (((2*sub+hf)*16) ^ rs), kk);
      }
      char* vb = Vsb + r*256;
      #pragma unroll
      for (int hf = 0; hf < 2; ++hf) {
        float vv[8];
        #pragma unroll
        for (int i = 0; i < 8; ++i) {
          float d_; DOT64(d_, row, Wq + (128+db+hf*8+i)*64);
          vv[i] = d_ + Bq[128+db+hf*8+i];
        }
        const int so = (2*sub+hf)*32;
        *(float4*)(vb + ((so     ) ^ rs)) = make_float4(vv[0],vv[1],vv[2],vv[3]);
        *(float4*)(vb + ((so + 16) ^ rs)) = make_float4(vv[4],vv[5],vv[6],vv[7]);
      }
    }
    __syncthreads();

    // ---- attention: 2 heads/thread; K/V reads wave-uniform (broadcast) ----
    float attv[16];
    #pragma unroll
    for (int hf = 0; hf < 2; ++hf) {
      const int h = 2*sub + hf;
      const float q0=q[hf*8+0],q1=q[hf*8+1],q2=q[hf*8+2],q3=q[hf*8+3];
      const float q4=q[hf*8+4],q5=q[hf*8+5],q6=q[hf*8+6],q7=q[hf*8+7];
      float a0=0.f,a1=0.f,a2=0.f,a3=0.f,a4=0.f,a5=0.f,a6=0.f,a7=0.f,lsum=0.f;
      #pragma unroll 4
      for (int j = 0; j < SEQ; ++j) {
        const int jsw = (j&7)<<4;
        const uint4 kw = *(const uint4*)(Ksb + j*128 + ((h*16) ^ jsw));
        __half2 h0 = *(const __half2*)&kw.x;
        __half2 h1 = *(const __half2*)&kw.y;
        __half2 h2 = *(const __half2*)&kw.z;
        __half2 h3 = *(const __half2*)&kw.w;
        float2 f0 = __half22float2(h0), f1 = __half22float2(h1);
        float2 f2 = __half22float2(h2), f3 = __half22float2(h3);
        float sA = fmaf(q0,f0.x, q1*f0.y) + fmaf(q2,f1.x, q3*f1.y);
        float sB = fmaf(q4,f2.x, q5*f2.y) + fmaf(q6,f3.x, q7*f3.y);
        float p = exp2f(sA + sB);           // bounded scores -> max-free softmax
        const char* vb = Vsb + j*256;
        float4 v0 = *(const float4*)(vb + ((h*32     ) ^ jsw));
        float4 v1 = *(const float4*)(vb + ((h*32 + 16) ^ jsw));
        lsum += p;
        a0 = fmaf(p, v0.x, a0); a1 = fmaf(p, v0.y, a1);
        a2 = fmaf(p, v0.z, a2); a3 = fmaf(p, v0.w, a3);
        a4 = fmaf(p, v1.x, a4); a5 = fmaf(p, v1.y, a5);
        a6 = fmaf(p, v1.z, a6); a7 = fmaf(p, v1.w, a7);
      }
      const float inv = 1.0f / lsum;
      attv[hf*8+0]=a0*inv; attv[hf*8+1]=a1*inv; attv[hf*8+2]=a2*inv; attv[hf*8+3]=a3*inv;
      attv[hf*8+4]=a4*inv; attv[hf*8+5]=a5*inv; attv[hf*8+6]=a6*inv; attv[hf*8+7]=a7*inv;
    }
    // residual (own chunks), then overwrite xs with attention output
    float res[16];
    rchunk8(xrb + (((2*sub  )*16) ^ rs), res);
    rchunk8(xrb + (((2*sub+1)*16) ^ rs), res+8);
    wchunk8(xrb + (((2*sub  )*16) ^ rs), attv);
    wchunk8(xrb + (((2*sub+1)*16) ^ rs), attv+8);
    __syncthreads();

    // ---- O-projection + residual + LN1 ----
    float y[16];
    {
      float arow[64];
      #pragma unroll
      for (int cc = 0; cc < 8; ++cc) rchunk8(xrb + ((cc*16) ^ rs), arow + cc*8);
      float p1 = 0.f, p2 = 0.f;
      #pragma unroll
      for (int i = 0; i < 16; ++i) {
        float d_; DOT64(d_, arow, Wo + (db+i)*64);
        y[i] = d_ + Bo[db+i] + res[i];
        p1 += y[i]; p2 = fmaf(y[i], y[i], p2);
      }
      lnb[(sub*SEQ + r)*2    ] = p1;
      lnb[(sub*SEQ + r)*2 + 1] = p2;
    }
    __syncthreads();
    {
      float t1 = lnb[(0*SEQ+r)*2] + lnb[(1*SEQ+r)*2] + lnb[(2*SEQ+r)*2] + lnb[(3*SEQ+r)*2];
      float t2 = lnb[(0*SEQ+r)*2+1] + lnb[(1*SEQ+r)*2+1] + lnb[(2*SEQ+r)*2+1] + lnb[(3*SEQ+r)*2+1];
      const float mean = t1 * (1.0f/64.0f);
      const float var  = t2 * (1.0f/64.0f) - mean*mean;
      const float rstd = rsqrtf(var + 1e-5f);
      float xn[16];
      #pragma unroll
      for (int i = 0; i < 16; ++i)
        xn[i] = (y[i]-mean)*rstd*G1[db+i] + B1[db+i];
      wchunk8(xrb + (((2*sub  )*16) ^ rs), xn);
      wchunk8(xrb + (((2*sub+1)*16) ^ rs), xn+8);
    }
    __syncthreads();

    // ---- FF: 64->256 gelu ->64, two 128-hidden passes (ffb overlays Ks/Vs) ----
    float out16[16] = {0.f,0.f,0.f,0.f,0.f,0.f,0.f,0.f,0.f,0.f,0.f,0.f,0.f,0.f,0.f,0.f};
    char* frb = ffb + r*256;
    for (int pass = 0; pass < 2; ++pass) {
      #pragma unroll
      for (int g = 0; g < 2; ++g) {
        // re-read input row each group (keeps row[64] out of the FF2 live range)
        float rowf[64];
        #pragma unroll
        for (int cc = 0; cc < 8; ++cc) rchunk8(xrb + ((cc*16) ^ rs), rowf + cc*8);
        float hv[16];
        #pragma unroll
        for (int i = 0; i < 16; ++i) {
          const int hi = pass*128 + sub*32 + g*16 + i;
          float d_; DOT64(d_, rowf, W1 + hi*64);
          d_ += Bf1[hi];
          hv[i] = 0.5f*d_*(1.0f + erff(d_*0.70710678118654752f));
        }
        wchunk8(frb + (((sub*4+g*2  )*16) ^ rs), hv);
        wchunk8(frb + (((sub*4+g*2+1)*16) ^ rs), hv+8);
      }
      __syncthreads();
      #pragma unroll
      for (int cc = 0; cc < 16; ++cc) {
        float gv[8]; rchunk8(frb + ((cc*16) ^ rs), gv);
        #pragma unroll
        for (int i = 0; i < 16; ++i) {
          const float* w = W2 + (db+i)*256 + pass*128 + cc*8;
          float acc = out16[i];
          acc = fmaf(gv[0], w[0], acc); acc = fmaf(gv[1], w[1], acc);
          acc = fmaf(gv[2], w[2], acc); acc = fmaf(gv[3], w[3], acc);
          acc = fmaf(gv[4], w[4], acc); acc = fmaf(gv[5], w[5], acc);
          acc = fmaf(gv[6], w[6], acc); acc = fmaf(gv[7], w[7], acc);
          out16[i] = acc;
        }
      }
      __syncthreads();
    }
    // residual + LN2
    {
      float res2[16];
      rchunk8(xrb + (((2*sub  )*16) ^ rs), res2);
      rchunk8(xrb + (((2*sub+1)*16) ^ rs), res2+8);
      float yv[16]; float t1 = 0.f, t2 = 0.f;
      #pragma unroll
      for (int i = 0; i < 16; ++i) {
        yv[i] = out16[i] + Bf2[db+i] + res2[i];
        t1 += yv[i]; t2 = fmaf(yv[i], yv[i], t2);
      }
      lnb[(sub*SEQ + r)*2    ] = t1;
      lnb[(sub*SEQ + r)*2 + 1] = t2;
      __syncthreads();
      float s1 = lnb[(0*SEQ+r)*2] + lnb[(1*SEQ+r)*2] + lnb[(2*SEQ+r)*2] + lnb[(3*SEQ+r)*2];
      float s2 = lnb[(0*SEQ+r)*2+1] + lnb[(1*SEQ+r)*2+1] + lnb[(2*SEQ+r)*2+1] + lnb[(3*SEQ+r)*2+1];
      const float mean = s1 * (1.0f/64.0f);
      const float var  = s2 * (1.0f/64.0f) - mean*mean;
      const float rstd = rsqrtf(var + 1e-5f);
      float xn[16];
      #pragma unroll
      for (int i = 0; i < 16; ++i)
        xn[i] = (yv[i]-mean)*rstd*G2[db+i] + B2[db+i];
      wchunk8(xrb + (((2*sub  )*16) ^ rs), xn);
      wchunk8(xrb + (((2*sub+1)*16) ^ rs), xn+8);
    }
    __syncthreads();
  }

  // ---- mean over sequence -> nf[b][s][d] ----
  if (t < 256) {
    const int d = t & 63, qu = t >> 6;
    const int coff = ((d>>3)<<4);
    const int lo = (d&7)<<1;
    float sm = 0.f;
    for (int rr = qu*64; rr < qu*64 + 64; ++rr) {
      const char* p = (const char*)xs + rr*128 + ((coff ^ ((rr&7)<<4)) + lo);
      sm += __half2float(*(const __half*)p);
    }
    lnb[qu*64 + d] = sm;
  }
  __syncthreads();
  if (t < 64) {
    float sm = lnb[t] + lnb[64+t] + lnb[128+t] + lnb[192+t];
    nf[((size_t)b*4 + s)*64 + t] = sm * (1.0f/256.0f);
  }
}

// ------------------------- graph head kernel (unchanged) -------------------------
__global__ __launch_bounds__(128) void head_kernel(
  const float* __restrict__ nf,
  const float* __restrict__ ws_w, const float* __restrict__ ws_b,
  const float* __restrict__ b_s,  const float* __restrict__ lambda_init,
  const float* __restrict__ mc_w1, const float* __restrict__ mc_b1,
  const float* __restrict__ mc_w2, const float* __restrict__ mc_b2,
  const float* __restrict__ g1w, const float* __restrict__ g1b,
  const float* __restrict__ g2w, const float* __restrict__ g2b,
  const float* __restrict__ cw1, const float* __restrict__ cb1,
  const float* __restrict__ cw2, const float* __restrict__ cb2,
  float* __restrict__ out)
{
  const int b = blockIdx.x, t = threadIdx.x;
  __shared__ float nfb[256];
  __shared__ float meannf[64];
  __shared__ float fafb[8];
  __shared__ float z1[32];
  __shared__ float normM[16];
  __shared__ float rs[4];
  __shared__ float xw[512];
  __shared__ float hmat[512];
  __shared__ float hw[1024];
  __shared__ float gv[256];
  __shared__ float r1[128];

  for (int i = t; i < 256; i += 128) nfb[i] = nf[b*256 + i];
  __syncthreads();
  if (t < 8) {
    const int i = t & 3;
    const float* w = ws_w + (t >> 2)*64;
    float acc = 0.f;
    for (int c = 0; c < 64; ++c) acc = fmaf(nfb[i*64+c], w[c], acc);
    fafb[t] = acc;
  }
  if (t >= 64 && t < 128) {
    const int d = t - 64;
    meannf[d] = 0.25f*(nfb[d] + nfb[64+d] + nfb[128+d] + nfb[192+d]);
  }
  __syncthreads();
  if (t < 32) {
    float acc = mc_b1[t];
    const float* w = mc_w1 + t*64;
    for (int c = 0; c < 64; ++c) acc = fmaf(meannf[c], w[c], acc);
    z1[t] = fmaxf(acc, 0.f);
  }
  __syncthreads();
  if (t == 0) {
    float li = mc_b2[0];
    for (int k = 0; k < 32; ++k) li = fmaf(z1[k], mc_w2[k], li);
    const float lam = (1.0f/(1.0f + __expf(-li))) * lambda_init[0];
    const float AB[4][4] = {{1,1,0,0},{1,1,1,1},{0,1,1,1},{0,1,1,1}};
    const float add = ws_b[0] + b_s[0];
    float sM[4][4], deg[4];
    for (int i = 0; i < 4; ++i) {
      float d_ = 0.f;
      for (int j = 0; j < 4; ++j) {
        sM[i][j] = 1.0f/(1.0f + __expf(-(fafb[i] + fafb[4+j] + add)));
        d_ += sM[i][j];
      }
      deg[i] = d_;
    }
    float A[4][4], dinv[4];
    for (int i = 0; i < 4; ++i)
      for (int j = 0; j < 4; ++j) {
        const float a_ = sM[i][j] / (deg[j] + 1e-8f);
        const float sh = fmaxf(a_ * AB[i][j], 0.f);
        A[i][j] = lam*((i==j) ? 1.f : 0.f) + (1.0f - lam)*sh;
      }
    for (int j = 0; j < 4; ++j) {
      float d_ = 0.f;
      for (int i = 0; i < 4; ++i) d_ += A[i][j];
      dinv[j] = (d_ > 0.f) ? rsqrtf(d_) : 0.f;
    }
    for (int i = 0; i < 4; ++i) {
      float r_ = 0.f;
      for (int j = 0; j < 4; ++j) {
        const float n_ = dinv[i]*A[i][j]*dinv[j];
        normM[i*4+j] = n_;
        r_ += n_;
      }
      rs[i] = r_;
    }
  }
  __syncthreads();
  for (int idx = t; idx < 512; idx += 128) {
    const int i = idx >> 7, f = idx & 127;
    float acc = 0.f;
    for (int c = 0; c < 64; ++c) acc = fmaf(nfb[i*64+c], g1w[c*128 + f], acc);
    xw[idx] = acc;
  }
  __syncthreads();
  for (int idx = t; idx < 512; idx += 128) {
    const int j = idx >> 7, f = idx & 127;
    float acc = g1b[f];
    #pragma unroll
    for (int i = 0; i < 4; ++i) acc = fmaf(normM[i*4+j], xw[i*128+f], acc);
    hmat[j*128+f] = fmaxf(acc, 0.f);
  }
  __syncthreads();
  for (int idx = t; idx < 1024; idx += 128) {
    const int i = idx >> 8, f = idx & 255;
    float acc = 0.f;
    for (int c = 0; c < 128; ++c) acc = fmaf(hmat[i*128+c], g2w[c*256+f], acc);
    hw[idx] = acc;
  }
  __syncthreads();
  for (int f = t; f < 256; f += 128) {
    float acc = 0.f;
    #pragma unroll
    for (int i = 0; i < 4; ++i) acc = fmaf(rs[i], hw[i*256+f], acc);
    gv[f] = 0.25f*acc + g2b[f];
  }
  __syncthreads();
  if (t < 128) {
    float acc = cb1[t];
    for (int c = 0; c < 256; ++c) acc = fmaf(gv[c], cw1[c*128+t], acc);
    r1[t] = fmaxf(acc, 0.f);
  }
  __syncthreads();
  if (t < 5) {
    float acc = cb2[t];
    for (int k = 0; k < 128; ++k) acc = fmaf(r1[k], cw2[k*5 + t], acc);
    out[b*5 + t] = acc;
  }
}

// ------------------------- launch -------------------------
extern "C" void kernel_launch(void* const* d_in, const int* in_sizes, int n_in,
                              void* d_out, int out_size, void* d_ws, size_t ws_size,
                              hipStream_t stream) {
  (void)in_sizes; (void)n_in; (void)out_size; (void)ws_size;
  const float* sens   = (const float*)d_in[0];
  const float* c1w    = (const float*)d_in[1];
  const float* c1b    = (const float*)d_in[2];
  const float* bn1g   = (const float*)d_in[3];
  const float* bn1b   = (const float*)d_in[4];
  const float* c2w    = (const float*)d_in[5];
  const float* c2b    = (const float*)d_in[6];
  const float* bn2g   = (const float*)d_in[7];
  const float* bn2b   = (const float*)d_in[8];
  const float* wqkv   = (const float*)d_in[9];
  const float* bqkv   = (const float*)d_in[10];
  const float* wo     = (const float*)d_in[11];
  const float* bo     = (const float*)d_in[12];
  const float* ln1g   = (const float*)d_in[13];
  const float* ln1b   = (const float*)d_in[14];
  const float* fw1    = (const float*)d_in[15];
  const float* fb1    = (const float*)d_in[16];
  const float* fw2    = (const float*)d_in[17];
  const float* fb2    = (const float*)d_in[18];
  const float* ln2g   = (const float*)d_in[19];
  const float* ln2b   = (const float*)d_in[20];
  const float* ws_w   = (const float*)d_in[21];
  const float* ws_b   = (const float*)d_in[22];
  const float* b_s    = (const float*)d_in[23];
  const float* lam0   = (const float*)d_in[24];
  const float* mc_w1  = (const float*)d_in[25];
  const float* mc_b1  = (const float*)d_in[26];
  const float* mc_w2  = (const float*)d_in[27];
  const float* mc_b2  = (const float*)d_in[28];
  const float* g1w    = (const float*)d_in[29];
  const float* g1b    = (const float*)d_in[30];
  const float* g2w    = (const float*)d_in[31];
  const float* g2b    = (const float*)d_in[32];
  const float* cw1    = (const float*)d_in[33];
  const float* cb1    = (const float*)d_in[34];
  const float* cw2    = (const float*)d_in[35];
  const float* cb2    = (const float*)d_in[36];

  float* x0 = (float*)d_ws;                                      // 16 MiB
  float* nf = (float*)((char*)d_ws + (size_t)NSENS*NB*SEQ*DM*4); // 64 KiB

  conv_kernel<<<NSENS*NB, 256, 0, stream>>>(sens, c1w, c1b, bn1g, bn1b,
                                            c2w, c2b, bn2g, bn2b, x0);
  tx_kernel<<<NSENS*NB, 1024, 0, stream>>>(x0, nf, wqkv, bqkv, wo, bo,
                                           ln1g, ln1b, fw1, fb1, fw2, fb2, ln2g, ln2b);
  head_kernel<<<NB, 128, 0, stream>>>(nf, ws_w, ws_b, b_s, lam0,
                                      mc_w1, mc_b1, mc_w2, mc_b2,
                                      g1w, g1b, g2w, g2b, cw1, cb1, cw2, cb2,
                                      (float*)d_out);
}

// Round 5
// 864.906 us; speedup vs baseline: 2.1709x; 1.2758x over previous
//
#include <hip/hip_runtime.h>
#include <hip/hip_fp16.h>

#define NSENS 4
#define NB    64
#define LIN   2048
#define C1N   32
#define LP1   512
#define C2N   64
#define SEQ   256
#define DM    64
#define H1S   516

// 32-element dot: xa = VGPR array, wp = wave-uniform fp32 pointer (s_load path)
#define DOT32(res, xa, wp) { \
  float _a0=0.f,_a1=0.f,_a2=0.f,_a3=0.f; \
  _Pragma("unroll") \
  for (int _c = 0; _c < 32; _c += 4) { \
    _a0 = fmaf((xa)[_c],   (wp)[_c],   _a0); \
    _a1 = fmaf((xa)[_c+1], (wp)[_c+1], _a1); \
    _a2 = fmaf((xa)[_c+2], (wp)[_c+2], _a2); \
    _a3 = fmaf((xa)[_c+3], (wp)[_c+3], _a3); \
  } \
  (res) = (_a0+_a1)+(_a2+_a3); \
}

// 8 fp16 values <-> 8 floats through one 16B LDS transaction
__device__ __forceinline__ void rchunk8(const char* p, float* o) {
  const uint4 w = *(const uint4*)p;
  float2 f;
  f = __half22float2(*(const __half2*)&w.x); o[0]=f.x; o[1]=f.y;
  f = __half22float2(*(const __half2*)&w.y); o[2]=f.x; o[3]=f.y;
  f = __half22float2(*(const __half2*)&w.z); o[4]=f.x; o[5]=f.y;
  f = __half22float2(*(const __half2*)&w.w); o[6]=f.x; o[7]=f.y;
}
__device__ __forceinline__ void wchunk8(char* p, const float* v) {
  __half2 h0 = __floats2half2_rn(v[0],v[1]);
  __half2 h1 = __floats2half2_rn(v[2],v[3]);
  __half2 h2 = __floats2half2_rn(v[4],v[5]);
  __half2 h3 = __floats2half2_rn(v[6],v[7]);
  uint4 w;
  w.x = *(const unsigned*)&h0; w.y = *(const unsigned*)&h1;
  w.z = *(const unsigned*)&h2; w.w = *(const unsigned*)&h3;
  *(uint4*)p = w;
}

// ------------------------- conv branch kernel (unchanged) -------------------------
__global__ __launch_bounds__(256) void conv_kernel(
    const float* __restrict__ sens,
    const float* __restrict__ c1w, const float* __restrict__ c1b,
    const float* __restrict__ bn1g, const float* __restrict__ bn1b,
    const float* __restrict__ c2w, const float* __restrict__ c2b,
    const float* __restrict__ bn2g, const float* __restrict__ bn2b,
    float* __restrict__ x0)
{
  const int bid = blockIdx.x;
  const int s = bid >> 6, b = bid & 63;
  const int tid = threadIdx.x;
  __shared__ __half h1p[C1N][H1S];
  __shared__ float w2s[C1N*3*C2N];

  for (int i = tid; i < C1N*3*C2N; i += 256) {
    int co = i & 63; int rem = i >> 6; int k = rem % 3; int ci = rem / 3;
    w2s[(ci*3 + k)*64 + co] = c2w[((s*C2N + co)*C1N + ci)*3 + k];
  }

  const float* xg = sens + (size_t)(s*NB + b)*LIN;
  const float bnr = rsqrtf(1.0f + 1e-5f);

  {
    const int c = tid & 31;
    const int l0 = tid >> 5;
    const float w0 = c1w[(s*C1N + c)*5 + 0];
    const float w1 = c1w[(s*C1N + c)*5 + 1];
    const float w2 = c1w[(s*C1N + c)*5 + 2];
    const float w3 = c1w[(s*C1N + c)*5 + 3];
    const float w4 = c1w[(s*C1N + c)*5 + 4];
    const float cb = c1b[s*C1N + c];
    const float sc = bn1g[s*C1N + c]*bnr;
    const float bt = bn1b[s*C1N + c];
    for (int l = l0; l < LP1; l += 8) {
      const int base = 4*l;
      float xm2 = (base-2 >= 0) ? xg[base-2] : 0.f;
      float xm1 = (base-1 >= 0) ? xg[base-1] : 0.f;
      float x0v = xg[base+0];
      float x1v = xg[base+1];
      float x2v = xg[base+2];
      float x3v = xg[base+3];
      float x4v = (base+4 < LIN) ? xg[base+4] : 0.f;
      float y0 = w0*xm2 + w1*xm1 + w2*x0v + w3*x1v + w4*x2v;
      float y1 = w0*x0v + w1*x1v + w2*x2v + w3*x3v + w4*x4v;
      y0 = (y0 + cb)*sc + bt;
      y1 = (y1 + cb)*sc + bt;
      h1p[c][l+1] = __float2half(fmaxf(fmaxf(y0, y1), 0.f));
      if (l == 0)      h1p[c][0]      = __float2half(0.f);
      if (l == LP1-1)  h1p[c][LP1+1]  = __float2half(0.f);
    }
  }
  __syncthreads();

  const int rg = tid & 31, cg = tid >> 5;
  const int c0 = cg*8;
  float cb2[8], sc2[8], bt2[8];
  #pragma unroll
  for (int cc = 0; cc < 8; ++cc) {
    cb2[cc] = c2b[s*C2N + c0 + cc];
    sc2[cc] = bn2g[s*C2N + c0 + cc]*bnr;
    bt2[cc] = bn2b[s*C2N + c0 + cc];
  }
  for (int it = 0; it < 4; ++it) {
    const int rA = 64*it + rg;
    const int rB = rA + 32;
    float acc[2][2][8] = {};
    for (int ci = 0; ci < C1N; ++ci) {
      const __half2 a01 = *(const __half2*)&h1p[ci][2*rA];
      const __half2 a23 = *(const __half2*)&h1p[ci][2*rA+2];
      const __half2 b01 = *(const __half2*)&h1p[ci][2*rB];
      const __half2 b23 = *(const __half2*)&h1p[ci][2*rB+2];
      const float hA[4] = { __low2float(a01), __high2float(a01), __low2float(a23), __high2float(a23) };
      const float hB[4] = { __low2float(b01), __high2float(b01), __low2float(b23), __high2float(b23) };
      #pragma unroll
      for (int k = 0; k < 3; ++k) {
        const float4 wv0 = *(const float4*)&w2s[(ci*3+k)*64 + c0];
        const float4 wv1 = *(const float4*)&w2s[(ci*3+k)*64 + c0 + 4];
        const float wr[8] = {wv0.x, wv0.y, wv0.z, wv0.w, wv1.x, wv1.y, wv1.z, wv1.w};
        #pragma unroll
        for (int p = 0; p < 2; ++p) {
          const float xa = hA[k+p];
          const float xb = hB[k+p];
          #pragma unroll
          for (int cc = 0; cc < 8; ++cc) {
            acc[0][p][cc] = fmaf(wr[cc], xa, acc[0][p][cc]);
            acc[1][p][cc] = fmaf(wr[cc], xb, acc[1][p][cc]);
          }
        }
      }
    }
    #pragma unroll
    for (int rr = 0; rr < 2; ++rr) {
      const int r = rr ? rB : rA;
      float* outp = x0 + ((size_t)bid*SEQ + r)*DM + c0;
      #pragma unroll
      for (int cc = 0; cc < 8; ++cc) {
        float v0 = (acc[rr][0][cc] + cb2[cc])*sc2[cc] + bt2[cc];
        float v1 = (acc[rr][1][cc] + cb2[cc])*sc2[cc] + bt2[cc];
        float v = fmaxf(fmaxf(v0, v1), 0.f);
        const int d = c0 + cc;
        const float ang = (float)r * __expf(-0.14391156463f*(float)(d & ~1));
        const float pe = (d & 1) ? cosf(ang) : sinf(ang);
        outp[cc] = v + pe;
      }
    }
  }
}

// ---------- transformer kernel v5: half-split dots (<=60 live VGPR) ----------
// LDS map (136 KiB):
//   [0   , 32K )  xs  : __half [256 rows][64] packed, row=128B, XOR ((r&7)<<4)
//   [32K , 40K )  lnb : float  [4][256][2]
//   [40K , 72K )  Ks  : __half [j][h*8] packed, row=128B, XOR ((j&7)<<4)
//   [72K , 136K)  Vs  : float  [j][h*8], row=256B, XOR per 16B
//   attv buf (fp16 [256][64], 128B rows) and FF hidden (fp16 [256][128],
//   256B rows) overlay [40K,...) after Ks/Vs are dead.
__global__ __attribute__((amdgpu_waves_per_eu(4,4))) __launch_bounds__(1024) void tx_kernel(
  const float* __restrict__ x0, float* __restrict__ nf,
  const float* __restrict__ wqkv, const float* __restrict__ bqkv,
  const float* __restrict__ wo, const float* __restrict__ bo,
  const float* __restrict__ ln1g, const float* __restrict__ ln1b,
  const float* __restrict__ fw1, const float* __restrict__ fb1,
  const float* __restrict__ fw2, const float* __restrict__ fb2,
  const float* __restrict__ ln2g, const float* __restrict__ ln2b)
{
  __shared__ char smem[139264];
  __half* xs  = (__half*)(smem);
  float*  lnb = (float*)(smem + 32768);
  char*   Ksb = smem + 40960;
  char*   Vsb = smem + 73728;
  char*   ffb = smem + 40960;

  const int bid = blockIdx.x;
  const int s = bid >> 6, b = bid & 63;
  const int t = threadIdx.x;
  const int r = t & 255;
  const int sub = __builtin_amdgcn_readfirstlane(t >> 8);
  const int db = sub*16;
  const int rs = (r & 7) << 4;
  char* xrb = (char*)xs + r*128;

  // ---- load x0 row r, dims db..db+15, pack to fp16 ----
  {
    const float* xp = x0 + ((size_t)bid*SEQ + r)*DM + db;
    float v[16];
    #pragma unroll
    for (int i = 0; i < 16; i += 4) {
      float4 q4 = *(const float4*)(xp + i);
      v[i]=q4.x; v[i+1]=q4.y; v[i+2]=q4.z; v[i+3]=q4.w;
    }
    wchunk8(xrb + (((2*sub  )*16) ^ rs), v);
    wchunk8(xrb + (((2*sub+1)*16) ^ rs), v+8);
  }
  __syncthreads();

  const float qs = 0.35355339059327373f * 1.4426950408889634f; // 1/sqrt(8)*log2(e)

  for (int layer = 0; layer < 2; ++layer) {
    const int wi = s*2 + layer;
    const float* Wq  = wqkv + (size_t)wi*192*64;
    const float* Bq  = bqkv + wi*192;
    const float* Wo  = wo   + (size_t)wi*64*64;
    const float* Bo  = bo   + wi*64;
    const float* G1  = ln1g + wi*64;  const float* B1 = ln1b + wi*64;
    const float* W1  = fw1  + (size_t)wi*256*64;  const float* Bf1 = fb1 + wi*256;
    const float* W2  = fw2  + (size_t)wi*64*256;  const float* Bf2 = fb2 + wi*64;
    const float* G2  = ln2g + wi*64;  const float* B2 = ln2b + wi*64;

    // ---- K group: 16 outputs, half-split (acc[16] + rh[32] live) ----
    {
      float acc[16];
      #pragma unroll
      for (int i = 0; i < 16; ++i) acc[i] = Bq[64+db+i];
      #pragma unroll
      for (int half = 0; half < 2; ++half) {
        float rh[32];
        #pragma unroll
        for (int cc = 0; cc < 4; ++cc) rchunk8(xrb + (((half*4+cc)*16) ^ rs), rh + cc*8);
        #pragma unroll
        for (int i = 0; i < 16; ++i) {
          float d_; DOT32(d_, rh, Wq + (64+db+i)*64 + half*32);
          acc[i] += d_;
        }
      }
      char* kb = Ksb + r*128;
      wchunk8(kb + (((2*sub  )*16) ^ rs), acc);
      wchunk8(kb + (((2*sub+1)*16) ^ rs), acc+8);
    }
    // ---- V group ----
    {
      float acc[16];
      #pragma unroll
      for (int i = 0; i < 16; ++i) acc[i] = Bq[128+db+i];
      #pragma unroll
      for (int half = 0; half < 2; ++half) {
        float rh[32];
        #pragma unroll
        for (int cc = 0; cc < 4; ++cc) rchunk8(xrb + (((half*4+cc)*16) ^ rs), rh + cc*8);
        #pragma unroll
        for (int i = 0; i < 16; ++i) {
          float d_; DOT32(d_, rh, Wq + (128+db+i)*64 + half*32);
          acc[i] += d_;
        }
      }
      char* vb = Vsb + r*256;
      *(float4*)(vb + (((2*sub  )*32     ) ^ rs)) = make_float4(acc[0], acc[1], acc[2], acc[3]);
      *(float4*)(vb + (((2*sub  )*32 + 16) ^ rs)) = make_float4(acc[4], acc[5], acc[6], acc[7]);
      *(float4*)(vb + (((2*sub+1)*32     ) ^ rs)) = make_float4(acc[8], acc[9], acc[10],acc[11]);
      *(float4*)(vb + (((2*sub+1)*32 + 16) ^ rs)) = make_float4(acc[12],acc[13],acc[14],acc[15]);
    }
    // ---- Q group (result stays in registers) ----
    float q[16];
    {
      #pragma unroll
      for (int i = 0; i < 16; ++i) q[i] = Bq[db+i];
      #pragma unroll
      for (int half = 0; half < 2; ++half) {
        float rh[32];
        #pragma unroll
        for (int cc = 0; cc < 4; ++cc) rchunk8(xrb + (((half*4+cc)*16) ^ rs), rh + cc*8);
        #pragma unroll
        for (int i = 0; i < 16; ++i) {
          float d_; DOT32(d_, rh, Wq + (db+i)*64 + half*32);
          q[i] += d_;
        }
      }
      #pragma unroll
      for (int i = 0; i < 16; ++i) q[i] *= qs;
    }
    __syncthreads();

    // ---- attention: 2 heads/thread; K/V reads wave-uniform (broadcast) ----
    float attv[16];
    #pragma unroll
    for (int hf = 0; hf < 2; ++hf) {
      const int h = 2*sub + hf;
      const float q0=q[hf*8+0],q1=q[hf*8+1],q2=q[hf*8+2],q3=q[hf*8+3];
      const float q4=q[hf*8+4],q5=q[hf*8+5],q6=q[hf*8+6],q7=q[hf*8+7];
      float a0=0.f,a1=0.f,a2=0.f,a3=0.f,a4=0.f,a5=0.f,a6=0.f,a7=0.f,lsum=0.f;
      #pragma unroll 4
      for (int j = 0; j < SEQ; ++j) {
        const int jsw = (j&7)<<4;
        const uint4 kw = *(const uint4*)(Ksb + j*128 + ((h*16) ^ jsw));
        float2 f0 = __half22float2(*(const __half2*)&kw.x);
        float2 f1 = __half22float2(*(const __half2*)&kw.y);
        float2 f2 = __half22float2(*(const __half2*)&kw.z);
        float2 f3 = __half22float2(*(const __half2*)&kw.w);
        float sA = fmaf(q0,f0.x, q1*f0.y) + fmaf(q2,f1.x, q3*f1.y);
        float sB = fmaf(q4,f2.x, q5*f2.y) + fmaf(q6,f3.x, q7*f3.y);
        float p = exp2f(sA + sB);           // bounded scores -> max-free softmax
        const char* vb = Vsb + j*256;
        float4 v0 = *(const float4*)(vb + ((h*32     ) ^ jsw));
        float4 v1 = *(const float4*)(vb + ((h*32 + 16) ^ jsw));
        lsum += p;
        a0 = fmaf(p, v0.x, a0); a1 = fmaf(p, v0.y, a1);
        a2 = fmaf(p, v0.z, a2); a3 = fmaf(p, v0.w, a3);
        a4 = fmaf(p, v1.x, a4); a5 = fmaf(p, v1.y, a5);
        a6 = fmaf(p, v1.z, a6); a7 = fmaf(p, v1.w, a7);
      }
      const float inv = 1.0f / lsum;
      attv[hf*8+0]=a0*inv; attv[hf*8+1]=a1*inv; attv[hf*8+2]=a2*inv; attv[hf*8+3]=a3*inv;
      attv[hf*8+4]=a4*inv; attv[hf*8+5]=a5*inv; attv[hf*8+6]=a6*inv; attv[hf*8+7]=a7*inv;
    }
    __syncthreads();                       // all Ks/Vs reads done
    // write attn output to attv buffer (overlays dead Ks); xs keeps residual
    {
      char* ab = ffb + r*128;
      wchunk8(ab + (((2*sub  )*16) ^ rs), attv);
      wchunk8(ab + (((2*sub+1)*16) ^ rs), attv+8);
    }
    __syncthreads();

    // ---- O-projection + residual + LN1 ----
    float y[16];
    {
      float acc[16];
      #pragma unroll
      for (int i = 0; i < 16; ++i) acc[i] = Bo[db+i];
      const char* ab = ffb + r*128;
      #pragma unroll
      for (int half = 0; half < 2; ++half) {
        float rh[32];
        #pragma unroll
        for (int cc = 0; cc < 4; ++cc) rchunk8(ab + (((half*4+cc)*16) ^ rs), rh + cc*8);
        #pragma unroll
        for (int i = 0; i < 16; ++i) {
          float d_; DOT32(d_, rh, Wo + (db+i)*64 + half*32);
          acc[i] += d_;
        }
      }
      float res[16];
      rchunk8(xrb + (((2*sub  )*16) ^ rs), res);
      rchunk8(xrb + (((2*sub+1)*16) ^ rs), res+8);
      float p1 = 0.f, p2 = 0.f;
      #pragma unroll
      for (int i = 0; i < 16; ++i) {
        y[i] = acc[i] + res[i];
        p1 += y[i]; p2 = fmaf(y[i], y[i], p2);
      }
      lnb[(sub*SEQ + r)*2    ] = p1;
      lnb[(sub*SEQ + r)*2 + 1] = p2;
    }
    __syncthreads();
    {
      float t1 = lnb[(0*SEQ+r)*2] + lnb[(1*SEQ+r)*2] + lnb[(2*SEQ+r)*2] + lnb[(3*SEQ+r)*2];
      float t2 = lnb[(0*SEQ+r)*2+1] + lnb[(1*SEQ+r)*2+1] + lnb[(2*SEQ+r)*2+1] + lnb[(3*SEQ+r)*2+1];
      const float mean = t1 * (1.0f/64.0f);
      const float var  = t2 * (1.0f/64.0f) - mean*mean;
      const float rstd = rsqrtf(var + 1e-5f);
      float xn[16];
      #pragma unroll
      for (int i = 0; i < 16; ++i)
        xn[i] = (y[i]-mean)*rstd*G1[db+i] + B1[db+i];
      wchunk8(xrb + (((2*sub  )*16) ^ rs), xn);
      wchunk8(xrb + (((2*sub+1)*16) ^ rs), xn+8);
    }
    __syncthreads();

    // ---- FF: 64->256 gelu ->64, two 128-hidden passes ----
    float out16[16] = {0.f,0.f,0.f,0.f,0.f,0.f,0.f,0.f,0.f,0.f,0.f,0.f,0.f,0.f,0.f,0.f};
    char* frb = ffb + r*256;
    for (int pass = 0; pass < 2; ++pass) {
      #pragma unroll
      for (int g = 0; g < 2; ++g) {
        float acc[16];
        #pragma unroll
        for (int i = 0; i < 16; ++i) acc[i] = Bf1[pass*128 + sub*32 + g*16 + i];
        #pragma unroll
        for (int half = 0; half < 2; ++half) {
          float rh[32];
          #pragma unroll
          for (int cc = 0; cc < 4; ++cc) rchunk8(xrb + (((half*4+cc)*16) ^ rs), rh + cc*8);
          #pragma unroll
          for (int i = 0; i < 16; ++i) {
            float d_; DOT32(d_, rh, W1 + (pass*128 + sub*32 + g*16 + i)*64 + half*32);
            acc[i] += d_;
          }
        }
        #pragma unroll
        for (int i = 0; i < 16; ++i)
          acc[i] = 0.5f*acc[i]*(1.0f + erff(acc[i]*0.70710678118654752f));
        wchunk8(frb + (((sub*4+g*2  )*16) ^ rs), acc);
        wchunk8(frb + (((sub*4+g*2+1)*16) ^ rs), acc+8);
      }
      __syncthreads();
      #pragma unroll
      for (int cc = 0; cc < 16; ++cc) {
        float gv[8]; rchunk8(frb + ((cc*16) ^ rs), gv);
        #pragma unroll
        for (int i = 0; i < 16; ++i) {
          const float* w = W2 + (db+i)*256 + pass*128 + cc*8;
          float acc = out16[i];
          acc = fmaf(gv[0], w[0], acc); acc = fmaf(gv[1], w[1], acc);
          acc = fmaf(gv[2], w[2], acc); acc = fmaf(gv[3], w[3], acc);
          acc = fmaf(gv[4], w[4], acc); acc = fmaf(gv[5], w[5], acc);
          acc = fmaf(gv[6], w[6], acc); acc = fmaf(gv[7], w[7], acc);
          out16[i] = acc;
        }
      }
      __syncthreads();
    }
    // residual + LN2
    {
      float res2[16];
      rchunk8(xrb + (((2*sub  )*16) ^ rs), res2);
      rchunk8(xrb + (((2*sub+1)*16) ^ rs), res2+8);
      float yv[16]; float t1 = 0.f, t2 = 0.f;
      #pragma unroll
      for (int i = 0; i < 16; ++i) {
        yv[i] = out16[i] + Bf2[db+i] + res2[i];
        t1 += yv[i]; t2 = fmaf(yv[i], yv[i], t2);
      }
      lnb[(sub*SEQ + r)*2    ] = t1;
      lnb[(sub*SEQ + r)*2 + 1] = t2;
      __syncthreads();
      float s1 = lnb[(0*SEQ+r)*2] + lnb[(1*SEQ+r)*2] + lnb[(2*SEQ+r)*2] + lnb[(3*SEQ+r)*2];
      float s2 = lnb[(0*SEQ+r)*2+1] + lnb[(1*SEQ+r)*2+1] + lnb[(2*SEQ+r)*2+1] + lnb[(3*SEQ+r)*2+1];
      const float mean = s1 * (1.0f/64.0f);
      const float var  = s2 * (1.0f/64.0f) - mean*mean;
      const float rstd = rsqrtf(var + 1e-5f);
      float xn[16];
      #pragma unroll
      for (int i = 0; i < 16; ++i)
        xn[i] = (yv[i]-mean)*rstd*G2[db+i] + B2[db+i];
      wchunk8(xrb + (((2*sub  )*16) ^ rs), xn);
      wchunk8(xrb + (((2*sub+1)*16) ^ rs), xn+8);
    }
    __syncthreads();
  }

  // ---- mean over sequence -> nf[b][s][d] ----
  if (t < 256) {
    const int d = t & 63, qu = t >> 6;
    const int coff = ((d>>3)<<4);
    const int lo = (d&7)<<1;
    float sm = 0.f;
    for (int rr = qu*64; rr < qu*64 + 64; ++rr) {
      const char* p = (const char*)xs + rr*128 + ((coff ^ ((rr&7)<<4)) + lo);
      sm += __half2float(*(const __half*)p);
    }
    lnb[qu*64 + d] = sm;
  }
  __syncthreads();
  if (t < 64) {
    float sm = lnb[t] + lnb[64+t] + lnb[128+t] + lnb[192+t];
    nf[((size_t)b*4 + s)*64 + t] = sm * (1.0f/256.0f);
  }
}

// ------------------------- graph head kernel (unchanged) -------------------------
__global__ __launch_bounds__(128) void head_kernel(
  const float* __restrict__ nf,
  const float* __restrict__ ws_w, const float* __restrict__ ws_b,
  const float* __restrict__ b_s,  const float* __restrict__ lambda_init,
  const float* __restrict__ mc_w1, const float* __restrict__ mc_b1,
  const float* __restrict__ mc_w2, const float* __restrict__ mc_b2,
  const float* __restrict__ g1w, const float* __restrict__ g1b,
  const float* __restrict__ g2w, const float* __restrict__ g2b,
  const float* __restrict__ cw1, const float* __restrict__ cb1,
  const float* __restrict__ cw2, const float* __restrict__ cb2,
  float* __restrict__ out)
{
  const int b = blockIdx.x, t = threadIdx.x;
  __shared__ float nfb[256];
  __shared__ float meannf[64];
  __shared__ float fafb[8];
  __shared__ float z1[32];
  __shared__ float normM[16];
  __shared__ float rs[4];
  __shared__ float xw[512];
  __shared__ float hmat[512];
  __shared__ float hw[1024];
  __shared__ float gv[256];
  __shared__ float r1[128];

  for (int i = t; i < 256; i += 128) nfb[i] = nf[b*256 + i];
  __syncthreads();
  if (t < 8) {
    const int i = t & 3;
    const float* w = ws_w + (t >> 2)*64;
    float acc = 0.f;
    for (int c = 0; c < 64; ++c) acc = fmaf(nfb[i*64+c], w[c], acc);
    fafb[t] = acc;
  }
  if (t >= 64 && t < 128) {
    const int d = t - 64;
    meannf[d] = 0.25f*(nfb[d] + nfb[64+d] + nfb[128+d] + nfb[192+d]);
  }
  __syncthreads();
  if (t < 32) {
    float acc = mc_b1[t];
    const float* w = mc_w1 + t*64;
    for (int c = 0; c < 64; ++c) acc = fmaf(meannf[c], w[c], acc);
    z1[t] = fmaxf(acc, 0.f);
  }
  __syncthreads();
  if (t == 0) {
    float li = mc_b2[0];
    for (int k = 0; k < 32; ++k) li = fmaf(z1[k], mc_w2[k], li);
    const float lam = (1.0f/(1.0f + __expf(-li))) * lambda_init[0];
    const float AB[4][4] = {{1,1,0,0},{1,1,1,1},{0,1,1,1},{0,1,1,1}};
    const float add = ws_b[0] + b_s[0];
    float sM[4][4], deg[4];
    for (int i = 0; i < 4; ++i) {
      float d_ = 0.f;
      for (int j = 0; j < 4; ++j) {
        sM[i][j] = 1.0f/(1.0f + __expf(-(fafb[i] + fafb[4+j] + add)));
        d_ += sM[i][j];
      }
      deg[i] = d_;
    }
    float A[4][4], dinv[4];
    for (int i = 0; i < 4; ++i)
      for (int j = 0; j < 4; ++j) {
        const float a_ = sM[i][j] / (deg[j] + 1e-8f);
        const float sh = fmaxf(a_ * AB[i][j], 0.f);
        A[i][j] = lam*((i==j) ? 1.f : 0.f) + (1.0f - lam)*sh;
      }
    for (int j = 0; j < 4; ++j) {
      float d_ = 0.f;
      for (int i = 0; i < 4; ++i) d_ += A[i][j];
      dinv[j] = (d_ > 0.f) ? rsqrtf(d_) : 0.f;
    }
    for (int i = 0; i < 4; ++i) {
      float r_ = 0.f;
      for (int j = 0; j < 4; ++j) {
        const float n_ = dinv[i]*A[i][j]*dinv[j];
        normM[i*4+j] = n_;
        r_ += n_;
      }
      rs[i] = r_;
    }
  }
  __syncthreads();
  for (int idx = t; idx < 512; idx += 128) {
    const int i = idx >> 7, f = idx & 127;
    float acc = 0.f;
    for (int c = 0; c < 64; ++c) acc = fmaf(nfb[i*64+c], g1w[c*128 + f], acc);
    xw[idx] = acc;
  }
  __syncthreads();
  for (int idx = t; idx < 512; idx += 128) {
    const int j = idx >> 7, f = idx & 127;
    float acc = g1b[f];
    #pragma unroll
    for (int i = 0; i < 4; ++i) acc = fmaf(normM[i*4+j], xw[i*128+f], acc);
    hmat[j*128+f] = fmaxf(acc, 0.f);
  }
  __syncthreads();
  for (int idx = t; idx < 1024; idx += 128) {
    const int i = idx >> 8, f = idx & 255;
    float acc = 0.f;
    for (int c = 0; c < 128; ++c) acc = fmaf(hmat[i*128+c], g2w[c*256+f], acc);
    hw[idx] = acc;
  }
  __syncthreads();
  for (int f = t; f < 256; f += 128) {
    float acc = 0.f;
    #pragma unroll
    for (int i = 0; i < 4; ++i) acc = fmaf(rs[i], hw[i*256+f], acc);
    gv[f] = 0.25f*acc + g2b[f];
  }
  __syncthreads();
  if (t < 128) {
    float acc = cb1[t];
    for (int c = 0; c < 256; ++c) acc = fmaf(gv[c], cw1[c*128+t], acc);
    r1[t] = fmaxf(acc, 0.f);
  }
  __syncthreads();
  if (t < 5) {
    float acc = cb2[t];
    for (int k = 0; k < 128; ++k) acc = fmaf(r1[k], cw2[k*5 + t], acc);
    out[b*5 + t] = acc;
  }
}

// ------------------------- launch -------------------------
extern "C" void kernel_launch(void* const* d_in, const int* in_sizes, int n_in,
                              void* d_out, int out_size, void* d_ws, size_t ws_size,
                              hipStream_t stream) {
  (void)in_sizes; (void)n_in; (void)out_size; (void)ws_size;
  const float* sens   = (const float*)d_in[0];
  const float* c1w    = (const float*)d_in[1];
  const float* c1b    = (const float*)d_in[2];
  const float* bn1g   = (const float*)d_in[3];
  const float* bn1b   = (const float*)d_in[4];
  const float* c2w    = (const float*)d_in[5];
  const float* c2b    = (const float*)d_in[6];
  const float* bn2g   = (const float*)d_in[7];
  const float* bn2b   = (const float*)d_in[8];
  const float* wqkv   = (const float*)d_in[9];
  const float* bqkv   = (const float*)d_in[10];
  const float* wo     = (const float*)d_in[11];
  const float* bo     = (const float*)d_in[12];
  const float* ln1g   = (const float*)d_in[13];
  const float* ln1b   = (const float*)d_in[14];
  const float* fw1    = (const float*)d_in[15];
  const float* fb1    = (const float*)d_in[16];
  const float* fw2    = (const float*)d_in[17];
  const float* fb2    = (const float*)d_in[18];
  const float* ln2g   = (const float*)d_in[19];
  const float* ln2b   = (const float*)d_in[20];
  const float* ws_w   = (const float*)d_in[21];
  const float* ws_b   = (const float*)d_in[22];
  const float* b_s    = (const float*)d_in[23];
  const float* lam0   = (const float*)d_in[24];
  const float* mc_w1  = (const float*)d_in[25];
  const float* mc_b1  = (const float*)d_in[26];
  const float* mc_w2  = (const float*)d_in[27];
  const float* mc_b2  = (const float*)d_in[28];
  const float* g1w    = (const float*)d_in[29];
  const float* g1b    = (const float*)d_in[30];
  const float* g2w    = (const float*)d_in[31];
  const float* g2b    = (const float*)d_in[32];
  const float* cw1    = (const float*)d_in[33];
  const float* cb1    = (const float*)d_in[34];
  const float* cw2    = (const float*)d_in[35];
  const float* cb2    = (const float*)d_in[36];

  float* x0 = (float*)d_ws;                                      // 16 MiB
  float* nf = (float*)((char*)d_ws + (size_t)NSENS*NB*SEQ*DM*4); // 64 KiB

  conv_kernel<<<NSENS*NB, 256, 0, stream>>>(sens, c1w, c1b, bn1g, bn1b,
                                            c2w, c2b, bn2g, bn2b, x0);
  tx_kernel<<<NSENS*NB, 1024, 0, stream>>>(x0, nf, wqkv, bqkv, wo, bo,
                                           ln1g, ln1b, fw1, fb1, fw2, fb2, ln2g, ln2b);
  head_kernel<<<NB, 128, 0, stream>>>(nf, ws_w, ws_b, b_s, lam0,
                                      mc_w1, mc_b1, mc_w2, mc_b2,
                                      g1w, g1b, g2w, g2b, cw1, cb1, cw2, cb2,
                                      (float*)d_out);
}